// Round 18
// baseline (130.531 us; speedup 1.0000x reference)
//
#include <hip/hip_runtime.h>
#include <hip/hip_bf16.h>

typedef __attribute__((ext_vector_type(4))) float f32x4;
typedef __attribute__((ext_vector_type(16))) float f32x16;
typedef __attribute__((ext_vector_type(8))) __bf16 bf16x8;
typedef __attribute__((ext_vector_type(4))) __bf16 bf16x4;
typedef __attribute__((ext_vector_type(2))) __bf16 bf16x2;
typedef __attribute__((ext_vector_type(4))) unsigned u32x4;
typedef __attribute__((ext_vector_type(2))) unsigned u32x2;

#define VTS 264  // attn V^T LDS stride
#define KLS 40   // attn K LDS stride (80B rows, 16B-aligned)
#define L2E 1.4426950408889634f

#define GLOAD_LDS16(g, l) __builtin_amdgcn_global_load_lds( \
    (const __attribute__((address_space(1))) void*)(g),     \
    (__attribute__((address_space(3))) void*)(l), 16, 0, 0)

// exchange: a' = (a_lo, b_lo) ; b' = (a_hi, b_hi). Operands MUST be distinct
// values (HW RMWs two registers; self-aliased operands corrupt — R7-R9 bug).
#if __has_builtin(__builtin_amdgcn_permlane32_swap)
#define SWP(a, b) { u32x2 _r = __builtin_amdgcn_permlane32_swap((a), (b), false, false); \
                    (a) = _r[0]; (b) = _r[1]; }
#else
#define SWP(a, b) { unsigned _sa = __shfl_xor((a), 32), _sb = __shfl_xor((b), 32); \
                    unsigned _na = hi ? _sb : (a); (b) = hi ? (b) : _sa; (a) = _na; }
#endif
#define SUM32(ts, lrun) { (lrun) += (ts) + __shfl_xor((ts), 32); }

// ---------------- merged setup: ln (0..8191) | bias (8192..8447) | prep (8448..9727) ----------------
__global__ __launch_bounds__(256) void setup_kernel(
    const float* __restrict__ msa, const float* __restrict__ g,
    const float* __restrict__ b, __bf16* __restrict__ xn,
    const float* __restrict__ pair, const float* __restrict__ Wb,
    const float* __restrict__ bb, float* __restrict__ biasf,
    const float* __restrict__ Wq, const float* __restrict__ Wk,
    const float* __restrict__ Wv, const float* __restrict__ Wg,
    const float* __restrict__ Wo, __bf16* __restrict__ Wt)
{
  __shared__ float wbs[1024];
  const int bid = blockIdx.x;
  const int t = threadIdx.x;
  if (bid < 8192) {
    const int row = bid * 4 + (t >> 6);
    const int lane = t & 63;
    f32x4 x = *(const f32x4*)(msa + (size_t)row * 256 + lane * 4);
    float s = x[0] + x[1] + x[2] + x[3];
    float s2 = x[0]*x[0] + x[1]*x[1] + x[2]*x[2] + x[3]*x[3];
#pragma unroll
    for (int d = 32; d >= 1; d >>= 1) {
      s  += __shfl_xor(s, d);
      s2 += __shfl_xor(s2, d);
    }
    const float mu  = s * (1.f / 256.f);
    const float inv = rsqrtf(s2 * (1.f / 256.f) - mu * mu + 1e-5f);
    const f32x4 gv = *(const f32x4*)(g + lane * 4);
    const f32x4 bv = *(const f32x4*)(b + lane * 4);
    bf16x4 o;
#pragma unroll
    for (int j = 0; j < 4; ++j) o[j] = (__bf16)((x[j] - mu) * inv * gv[j] + bv[j]);
    *(bf16x4*)(xn + (size_t)row * 256 + lane * 4) = o;
  } else if (bid < 8448) {
#pragma unroll
    for (int r2 = 0; r2 < 4; ++r2) wbs[t + 256 * r2] = Wb[t + 256 * r2];
    __syncthreads();
    const int i = bid - 8192, j = t;
    const float* src = pair + ((size_t)i * 256 + j) * 128;
    float acc[8];
#pragma unroll
    for (int hh = 0; hh < 8; ++hh) acc[hh] = bb[hh];
    for (int p = 0; p < 128; p += 4) {
      const f32x4 pv = *(const f32x4*)(src + p);
#pragma unroll
      for (int q2 = 0; q2 < 4; ++q2)
#pragma unroll
        for (int hh = 0; hh < 8; ++hh) acc[hh] += pv[q2] * wbs[(p + q2) * 8 + hh];
    }
#pragma unroll
    for (int hh = 0; hh < 8; ++hh)
      biasf[((size_t)hh * 256 + i) * 256 + j] = acc[hh] * L2E;
  } else {
    const int idx = bid - 8448;
    const int w = idx >> 8, n2 = idx & 255, k = t;
    const float* W = (w == 0) ? Wq : (w == 1) ? Wk : (w == 2) ? Wv : (w == 3) ? Wg : Wo;
    Wt[((size_t)w * 256 + n2) * 256 + k] = (__bf16)W[(size_t)k * 256 + n2];
  }
}

// ---- fused Q/K/V/Gate GEMM: BM=256, BN=128, 512 threads, XCD-banded (R17-proven) ----
__global__ __launch_bounds__(512, 4) void qkvg_gemm(
    const __bf16* __restrict__ xn, const __bf16* __restrict__ Wt,
    const float* __restrict__ bq, const float* __restrict__ bk,
    const float* __restrict__ bv, const float* __restrict__ bg,
    __bf16* __restrict__ qb, __bf16* __restrict__ kb,
    __bf16* __restrict__ vb, __bf16* __restrict__ gateb)
{
  __shared__ alignas(16) __bf16 Al[256 * 64];   // 32 KB
  __shared__ alignas(16) __bf16 Bl[128 * 64];   // 16 KB
  const int t = threadIdx.x;
  const int wave = t >> 6, lane = t & 63;
  const int l15 = lane & 15, l16 = lane >> 4;
  const int bid = blockIdx.x;
  const int xcd = bid & 7, idx = bid >> 3;
  const int m0 = (xcd * 16 + (idx & 15)) * 256;
  const int bn = idx >> 4;
  const int w = bn >> 1;
  const int nloc0 = (bn & 1) * 128;
  const __bf16* Wtw = Wt + (size_t)w * 65536;
  const int wm = (wave >> 1) * 64, wn = (wave & 1) * 64;

  const int srow = (lane >> 3);
  const int chunk = ((lane & 7) ^ srow) * 8;

  f32x4 acc[4][4];
#pragma unroll
  for (int i = 0; i < 4; ++i)
#pragma unroll
    for (int j = 0; j < 4; ++j) acc[i][j] = (f32x4){0.f, 0.f, 0.f, 0.f};

  for (int kt = 0; kt < 4; ++kt) {
    const int k0 = kt * 64;
#pragma unroll
    for (int i = 0; i < 4; ++i) {
      const int row = (wave * 4 + i) * 8 + srow;
      GLOAD_LDS16(xn + (size_t)(m0 + row) * 256 + k0 + chunk, &Al[(wave * 4 + i) * 512]);
    }
#pragma unroll
    for (int i = 0; i < 2; ++i) {
      const int row = (wave * 2 + i) * 8 + srow;
      GLOAD_LDS16(Wtw + (size_t)(nloc0 + row) * 256 + k0 + chunk, &Bl[(wave * 2 + i) * 512]);
    }
    __syncthreads();
#pragma unroll
    for (int kk = 0; kk < 2; ++kk) {
      bf16x8 a[4], bfr[4];
#pragma unroll
      for (int mi = 0; mi < 4; ++mi) {
        const int row = wm + mi * 16 + l15;
        a[mi] = *(const bf16x8*)&Al[row * 64 + ((kk * 32 + l16 * 8) ^ ((row & 7) << 3))];
      }
#pragma unroll
      for (int ni = 0; ni < 4; ++ni) {
        const int row = wn + ni * 16 + l15;
        bfr[ni] = *(const bf16x8*)&Bl[row * 64 + ((kk * 32 + l16 * 8) ^ ((row & 7) << 3))];
      }
#pragma unroll
      for (int mi = 0; mi < 4; ++mi)
#pragma unroll
        for (int ni = 0; ni < 4; ++ni)
          acc[mi][ni] = __builtin_amdgcn_mfma_f32_16x16x32_bf16(a[mi], bfr[ni], acc[mi][ni], 0, 0, 0);
    }
    __syncthreads();
  }

  const float* bias_arr = (w == 0) ? bq : (w == 1) ? bk : (w == 2) ? bv : bg;
  float bnis[4];
#pragma unroll
  for (int ni = 0; ni < 4; ++ni) bnis[ni] = bias_arr[nloc0 + wn + ni * 16 + l15];
  const float qscale = 0.17677669529663687f * L2E;

#pragma unroll
  for (int mi = 0; mi < 4; ++mi)
#pragma unroll
    for (int ni = 0; ni < 4; ++ni)
#pragma unroll
      for (int r = 0; r < 4; ++r) {
        const int grow = m0 + wm + mi * 16 + l16 * 4 + r;
        const int gcol = nloc0 + wn + ni * 16 + l15;
        const float v = acc[mi][ni][r] + bnis[ni];
        const int n = grow >> 8, i2 = grow & 255, h = gcol >> 5, dh = gcol & 31;
        const size_t hoff = (((size_t)n * 8 + h) * 256 + i2) * 32 + dh;
        if (w == 0)      qb[hoff] = (__bf16)(v * qscale);
        else if (w == 1) kb[hoff] = (__bf16)v;
        else if (w == 2) vb[hoff] = (__bf16)v;
        else gateb[(size_t)grow * 256 + gcol] = (__bf16)(1.f / (1.f + __expf(-v)));
      }
}

// ---- flash attention: 4 waves x 2 q-tiles (dual-chain ILP), K+V in LDS ----
__device__ __forceinline__ unsigned pk2(float a, float b) {
  bf16x2 t; t[0] = (__bf16)a; t[1] = (__bf16)b;
  return __builtin_bit_cast(unsigned, t);
}

__global__ __launch_bounds__(256, 4) void attn_kernel(
    const __bf16* __restrict__ qb, const __bf16* __restrict__ kb,
    const __bf16* __restrict__ vb, const float* __restrict__ biasf,
    const int* __restrict__ mask, __bf16* __restrict__ opre)
{
  __shared__ alignas(16) __bf16 Kl[256 * KLS];  // K [key][dh], 20KB
  __shared__ alignas(16) __bf16 Vt[32 * VTS];   // V^T [dh][key], 16.9KB
  __shared__ alignas(16) float Ml[256];          // additive mask
  const int t = threadIdx.x, wave = t >> 6, lane = t & 63;
  const int l31 = lane & 31, hi = lane >> 5;
  const int nh = blockIdx.x;
  const int n = nh >> 3, h = nh & 7;
  const __bf16* qbh = qb + (size_t)nh * 8192;

  { // stage K + V^T + mask — R13-exact pattern (0 bank conflicts)
    const bf16x8* ks = (const bf16x8*)(kb + (size_t)nh * 8192 + t * 32);
    bf16x8 kr[4];
#pragma unroll
    for (int j = 0; j < 4; ++j) kr[j] = ks[j];
#pragma unroll
    for (int j = 0; j < 4; ++j) *(bf16x8*)&Kl[t * KLS + j * 8] = kr[j];
    const bf16x8* vs = (const bf16x8*)(vb + (size_t)nh * 8192 + t * 32);
    bf16x8 vv[4];
#pragma unroll
    for (int j = 0; j < 4; ++j) vv[j] = vs[j];
#pragma unroll
    for (int j = 0; j < 4; ++j)
#pragma unroll
      for (int e = 0; e < 8; ++e) Vt[(j * 8 + e) * VTS + t] = vv[j][e];
    Ml[t] = mask[n * 256 + t] ? 0.f : -1e9f;
  }
  __syncthreads();

  const int qA = wave * 64 + l31;
  const int qB = qA + 32;
  const bf16x8 QfA0 = *(const bf16x8*)(qbh + (size_t)qA * 32 + hi * 8);
  const bf16x8 QfA1 = *(const bf16x8*)(qbh + (size_t)qA * 32 + 16 + hi * 8);
  const bf16x8 QfB0 = *(const bf16x8*)(qbh + (size_t)qB * 32 + hi * 8);
  const bf16x8 QfB1 = *(const bf16x8*)(qbh + (size_t)qB * 32 + 16 + hi * 8);

  const float* bpA = biasf + (size_t)h * 65536 + (size_t)qA * 256;
  const float* bpB = biasf + (size_t)h * 65536 + (size_t)qB * 256;

  f32x16 OtA, OtB;
#pragma unroll
  for (int r = 0; r < 16; ++r) { OtA[r] = 0.f; OtB[r] = 0.f; }
  float lrunA = 0.f, lrunB = 0.f;

#pragma unroll 1
  for (int kt = 0; kt < 8; ++kt) {
    const int k0 = kt * 32;
    const bf16x8 Kf0 = *(const bf16x8*)&Kl[(k0 + l31) * KLS + hi * 8];
    const bf16x8 Kf1 = *(const bf16x8*)&Kl[(k0 + l31) * KLS + 16 + hi * 8];
    const bf16x8 Vf0 = *(const bf16x8*)&Vt[l31 * VTS + k0 + hi * 8];
    const bf16x8 Vf1 = *(const bf16x8*)&Vt[l31 * VTS + k0 + 16 + hi * 8];
    // dual st-init: bias + mask loaded directly (sibling chain hides latency)
    f32x16 stA, stB;
#pragma unroll
    for (int g = 0; g < 4; ++g) {
      const f32x4 mk = *(const f32x4*)&Ml[k0 + 8 * g + 4 * hi];
      const f32x4 bvA = *(const f32x4*)(bpA + k0 + 8 * g + 4 * hi);
      const f32x4 bvB = *(const f32x4*)(bpB + k0 + 8 * g + 4 * hi);
#pragma unroll
      for (int e = 0; e < 4; ++e) {
        stA[4 * g + e] = bvA[e] + mk[e];
        stB[4 * g + e] = bvB[e] + mk[e];
      }
    }
    stA = __builtin_amdgcn_mfma_f32_32x32x16_bf16(Kf0, QfA0, stA, 0, 0, 0);
    stA = __builtin_amdgcn_mfma_f32_32x32x16_bf16(Kf1, QfA1, stA, 0, 0, 0);
    stB = __builtin_amdgcn_mfma_f32_32x32x16_bf16(Kf0, QfB0, stB, 0, 0, 0);
    stB = __builtin_amdgcn_mfma_f32_32x32x16_bf16(Kf1, QfB1, stB, 0, 0, 0);
    // softmax + pack + PV, chain A then chain B (scheduler interleaves)
    {
#pragma unroll
      for (int r = 0; r < 16; ++r) stA[r] = exp2f(stA[r]);
      float ts = stA[0];
#pragma unroll
      for (int r = 1; r < 16; ++r) ts += stA[r];
      SUM32(ts, lrunA);
      unsigned c0 = pk2(stA[0],  stA[1]),  c1 = pk2(stA[2],  stA[3]);
      unsigned c2 = pk2(stA[4],  stA[5]),  c3 = pk2(stA[6],  stA[7]);
      unsigned c4 = pk2(stA[8],  stA[9]),  c5 = pk2(stA[10], stA[11]);
      unsigned c6 = pk2(stA[12], stA[13]), c7 = pk2(stA[14], stA[15]);
      SWP(c0, c2); SWP(c1, c3); SWP(c4, c6); SWP(c5, c7);
      u32x4 w0 = {c0, c1, c2, c3}, w1 = {c4, c5, c6, c7};
      OtA = __builtin_amdgcn_mfma_f32_32x32x16_bf16(Vf0, __builtin_bit_cast(bf16x8, w0), OtA, 0, 0, 0);
      OtA = __builtin_amdgcn_mfma_f32_32x32x16_bf16(Vf1, __builtin_bit_cast(bf16x8, w1), OtA, 0, 0, 0);
    }
    {
#pragma unroll
      for (int r = 0; r < 16; ++r) stB[r] = exp2f(stB[r]);
      float ts = stB[0];
#pragma unroll
      for (int r = 1; r < 16; ++r) ts += stB[r];
      SUM32(ts, lrunB);
      unsigned c0 = pk2(stB[0],  stB[1]),  c1 = pk2(stB[2],  stB[3]);
      unsigned c2 = pk2(stB[4],  stB[5]),  c3 = pk2(stB[6],  stB[7]);
      unsigned c4 = pk2(stB[8],  stB[9]),  c5 = pk2(stB[10], stB[11]);
      unsigned c6 = pk2(stB[12], stB[13]), c7 = pk2(stB[14], stB[15]);
      SWP(c0, c2); SWP(c1, c3); SWP(c4, c6); SWP(c5, c7);
      u32x4 w0 = {c0, c1, c2, c3}, w1 = {c4, c5, c6, c7};
      OtB = __builtin_amdgcn_mfma_f32_32x32x16_bf16(Vf0, __builtin_bit_cast(bf16x8, w0), OtB, 0, 0, 0);
      OtB = __builtin_amdgcn_mfma_f32_32x32x16_bf16(Vf1, __builtin_bit_cast(bf16x8, w1), OtB, 0, 0, 0);
    }
  }

  // ---- epilogue x2: opre h-major [h][n][q][dh], permlane exchange, 2x16B stores ----
#pragma unroll
  for (int qt = 0; qt < 2; ++qt) {
    const f32x16& Ot = qt ? OtB : OtA;
    const float invl = 1.f / (qt ? lrunB : lrunA);
    const int q = qt ? qB : qA;
    unsigned P00 = pk2(Ot[0]  * invl, Ot[1]  * invl), P01 = pk2(Ot[2]  * invl, Ot[3]  * invl);
    unsigned P10 = pk2(Ot[4]  * invl, Ot[5]  * invl), P11 = pk2(Ot[6]  * invl, Ot[7]  * invl);
    unsigned P20 = pk2(Ot[8]  * invl, Ot[9]  * invl), P21 = pk2(Ot[10] * invl, Ot[11] * invl);
    unsigned P30 = pk2(Ot[12] * invl, Ot[13] * invl), P31 = pk2(Ot[14] * invl, Ot[15] * invl);
    SWP(P00, P20); SWP(P01, P21); SWP(P10, P30); SWP(P11, P31);
    u32x4 s0 = {P00, P01, P20, P21}, s1 = {P10, P11, P30, P31};
    __bf16* dst = opre + (((size_t)h * 128 + n) * 256 + q) * 32 + hi * 16;
    *(u32x4*)dst = s0;
    *(u32x4*)(dst + 8) = s1;
  }
}

// ---------------- output projection + gate, XCD-banded (memory-floor-bound) ----------------
__global__ __launch_bounds__(256) void wo_gemm(
    const __bf16* __restrict__ A, const __bf16* __restrict__ Wtw,
    const float* __restrict__ bo, const __bf16* __restrict__ gateb,
    float* __restrict__ out)
{
  __shared__ alignas(16) __bf16 Al[128 * 64];
  __shared__ alignas(16) __bf16 Bl[128 * 64];
  const int t = threadIdx.x;
  const int wave = t >> 6, lane = t & 63;
  const int l15 = lane & 15, l16 = lane >> 4;
  const int bid = blockIdx.x;
  const int xcd = bid & 7, idx = bid >> 3;
  const int m0 = (xcd * 32 + (idx & 31)) * 128;
  const int nloc0 = (idx >> 5) * 128;
  const int wm = (wave >> 1) * 64, wn = (wave & 1) * 64;

  const int srow = (lane >> 3);
  const int chunk = ((lane & 7) ^ srow) * 8;

  f32x4 acc[4][4];
#pragma unroll
  for (int i = 0; i < 4; ++i)
#pragma unroll
    for (int j = 0; j < 4; ++j) acc[i][j] = (f32x4){0.f, 0.f, 0.f, 0.f};

  for (int kt = 0; kt < 4; ++kt) {
    const int k0 = kt * 64;
#pragma unroll
    for (int i = 0; i < 4; ++i) {
      const int row = wave * 32 + i * 8 + srow;
      const int m = m0 + row;
      const int kg = k0 + chunk;
      GLOAD_LDS16(A + (size_t)(kg >> 5) * 1048576 + (size_t)(m >> 8) * 8192
                    + (m & 255) * 32 + (kg & 31),
                  &Al[(wave * 4 + i) * 512]);
      GLOAD_LDS16(Wtw + (size_t)(nloc0 + row) * 256 + kg, &Bl[(wave * 4 + i) * 512]);
    }
    __syncthreads();
#pragma unroll
    for (int kk = 0; kk < 2; ++kk) {
      bf16x8 a[4], bfr[4];
#pragma unroll
      for (int mi = 0; mi < 4; ++mi) {
        const int row = wm + mi * 16 + l15;
        a[mi] = *(const bf16x8*)&Al[row * 64 + ((kk * 32 + l16 * 8) ^ ((row & 7) << 3))];
      }
#pragma unroll
      for (int ni = 0; ni < 4; ++ni) {
        const int row = wn + ni * 16 + l15;
        bfr[ni] = *(const bf16x8*)&Bl[row * 64 + ((kk * 32 + l16 * 8) ^ ((row & 7) << 3))];
      }
#pragma unroll
      for (int mi = 0; mi < 4; ++mi)
#pragma unroll
        for (int ni = 0; ni < 4; ++ni)
          acc[mi][ni] = __builtin_amdgcn_mfma_f32_16x16x32_bf16(a[mi], bfr[ni], acc[mi][ni], 0, 0, 0);
    }
    __syncthreads();
  }

  float bov[4];
#pragma unroll
  for (int ni = 0; ni < 4; ++ni) bov[ni] = bo[nloc0 + wn + ni * 16 + l15];
#pragma unroll
  for (int mi = 0; mi < 4; ++mi)
#pragma unroll
    for (int ni = 0; ni < 4; ++ni)
#pragma unroll
      for (int r = 0; r < 4; ++r) {
        const int grow = m0 + wm + mi * 16 + l16 * 4 + r;
        const int gcol = nloc0 + wn + ni * 16 + l15;
        const size_t o = (size_t)grow * 256 + gcol;
        out[o] = (acc[mi][ni][r] + bov[ni]) * (float)gateb[o];
      }
}

extern "C" void kernel_launch(void* const* d_in, const int* in_sizes, int n_in,
                              void* d_out, int out_size, void* d_ws, size_t ws_size,
                              hipStream_t stream)
{
  const float* msa  = (const float*)d_in[0];
  const float* pair = (const float*)d_in[1];
  const int*   mask = (const int*)d_in[2];
  const float* ln_g = (const float*)d_in[3];
  const float* ln_b = (const float*)d_in[4];
  const float* Wq = (const float*)d_in[5];  const float* bq = (const float*)d_in[6];
  const float* Wk = (const float*)d_in[7];  const float* bk = (const float*)d_in[8];
  const float* Wv = (const float*)d_in[9];  const float* bv = (const float*)d_in[10];
  const float* Wb = (const float*)d_in[11]; const float* bb = (const float*)d_in[12];
  const float* Wo = (const float*)d_in[13]; const float* bo = (const float*)d_in[14];
  const float* Wg = (const float*)d_in[15]; const float* bg = (const float*)d_in[16];
  float* out = (float*)d_out;

  char* ws = (char*)d_ws;
  __bf16* xn    = (__bf16*)(ws);
  __bf16* qb    = (__bf16*)(ws + 16777216);
  __bf16* kb    = (__bf16*)(ws + 2 * 16777216);
  __bf16* vb    = (__bf16*)(ws + 3 * 16777216);
  __bf16* opre  = (__bf16*)(ws + 4 * 16777216);
  __bf16* Wt    = (__bf16*)(ws + 5 * 16777216);                      // 640KB
  __bf16* gateb = (__bf16*)(ws + 5 * 16777216 + 655360);             // 16.8MB
  float*  biasf = (float*)(ws + 5 * 16777216 + 655360 + 16777216);   // 2MB [h][q][k]

  hipLaunchKernelGGL(setup_kernel, dim3(9728), dim3(256), 0, stream,
                     msa, ln_g, ln_b, xn, pair, Wb, bb, biasf, Wq, Wk, Wv, Wg, Wo, Wt);
  hipLaunchKernelGGL(qkvg_gemm,   dim3(1024), dim3(512), 0, stream, xn, Wt, bq, bk, bv, bg, qb, kb, vb, gateb);
  hipLaunchKernelGGL(attn_kernel, dim3(1024), dim3(256), 0, stream, qb, kb, vb, biasf, mask, opre);
  hipLaunchKernelGGL(wo_gemm,     dim3(512),  dim3(256), 0, stream, opre, Wt + 4 * 65536, bo, gateb, out);
}

// Round 19
// 126.724 us; speedup vs baseline: 1.0300x; 1.0300x over previous
//
#include <hip/hip_runtime.h>
#include <hip/hip_bf16.h>

typedef __attribute__((ext_vector_type(4))) float f32x4;
typedef __attribute__((ext_vector_type(16))) float f32x16;
typedef __attribute__((ext_vector_type(8))) __bf16 bf16x8;
typedef __attribute__((ext_vector_type(4))) __bf16 bf16x4;
typedef __attribute__((ext_vector_type(2))) __bf16 bf16x2;
typedef __attribute__((ext_vector_type(4))) unsigned u32x4;
typedef __attribute__((ext_vector_type(2))) unsigned u32x2;

#define VTS 264  // attn V^T LDS stride
#define KLS 40   // attn K LDS stride (80B rows, 16B-aligned)
#define L2E 1.4426950408889634f

#define GLOAD_LDS16(g, l) __builtin_amdgcn_global_load_lds( \
    (const __attribute__((address_space(1))) void*)(g),     \
    (__attribute__((address_space(3))) void*)(l), 16, 0, 0)

// exchange: a' = (a_lo, b_lo) ; b' = (a_hi, b_hi). Operands MUST be distinct
// values (HW RMWs two registers; self-aliased operands corrupt — R7-R9 bug).
#if __has_builtin(__builtin_amdgcn_permlane32_swap)
#define SWP(a, b) { u32x2 _r = __builtin_amdgcn_permlane32_swap((a), (b), false, false); \
                    (a) = _r[0]; (b) = _r[1]; }
#else
#define SWP(a, b) { unsigned _sa = __shfl_xor((a), 32), _sb = __shfl_xor((b), 32); \
                    unsigned _na = hi ? _sb : (a); (b) = hi ? (b) : _sa; (a) = _na; }
#endif
#define SUM32(ts, lrun) { (lrun) += (ts) + __shfl_xor((ts), 32); }

// ---------------- merged setup: ln (0..8191) | bias (8192..8447) | prep (8448..9727) ----------------
__global__ __launch_bounds__(256) void setup_kernel(
    const float* __restrict__ msa, const float* __restrict__ g,
    const float* __restrict__ b, __bf16* __restrict__ xn,
    const float* __restrict__ pair, const float* __restrict__ Wb,
    const float* __restrict__ bb, float* __restrict__ biasf,
    const float* __restrict__ Wq, const float* __restrict__ Wk,
    const float* __restrict__ Wv, const float* __restrict__ Wg,
    const float* __restrict__ Wo, __bf16* __restrict__ Wt)
{
  __shared__ float wbs[1024];
  const int bid = blockIdx.x;
  const int t = threadIdx.x;
  if (bid < 8192) {
    const int row = bid * 4 + (t >> 6);
    const int lane = t & 63;
    f32x4 x = *(const f32x4*)(msa + (size_t)row * 256 + lane * 4);
    float s = x[0] + x[1] + x[2] + x[3];
    float s2 = x[0]*x[0] + x[1]*x[1] + x[2]*x[2] + x[3]*x[3];
#pragma unroll
    for (int d = 32; d >= 1; d >>= 1) {
      s  += __shfl_xor(s, d);
      s2 += __shfl_xor(s2, d);
    }
    const float mu  = s * (1.f / 256.f);
    const float inv = rsqrtf(s2 * (1.f / 256.f) - mu * mu + 1e-5f);
    const f32x4 gv = *(const f32x4*)(g + lane * 4);
    const f32x4 bv = *(const f32x4*)(b + lane * 4);
    bf16x4 o;
#pragma unroll
    for (int j = 0; j < 4; ++j) o[j] = (__bf16)((x[j] - mu) * inv * gv[j] + bv[j]);
    *(bf16x4*)(xn + (size_t)row * 256 + lane * 4) = o;
  } else if (bid < 8448) {
#pragma unroll
    for (int r2 = 0; r2 < 4; ++r2) wbs[t + 256 * r2] = Wb[t + 256 * r2];
    __syncthreads();
    const int i = bid - 8192, j = t;
    const float* src = pair + ((size_t)i * 256 + j) * 128;
    float acc[8];
#pragma unroll
    for (int hh = 0; hh < 8; ++hh) acc[hh] = bb[hh];
    for (int p = 0; p < 128; p += 4) {
      const f32x4 pv = *(const f32x4*)(src + p);
#pragma unroll
      for (int q2 = 0; q2 < 4; ++q2)
#pragma unroll
        for (int hh = 0; hh < 8; ++hh) acc[hh] += pv[q2] * wbs[(p + q2) * 8 + hh];
    }
#pragma unroll
    for (int hh = 0; hh < 8; ++hh)
      biasf[((size_t)hh * 256 + i) * 256 + j] = acc[hh] * L2E;
  } else {
    const int idx = bid - 8448;
    const int w = idx >> 8, n2 = idx & 255, k = t;
    const float* W = (w == 0) ? Wq : (w == 1) ? Wk : (w == 2) ? Wv : (w == 3) ? Wg : Wo;
    Wt[((size_t)w * 256 + n2) * 256 + k] = (__bf16)W[(size_t)k * 256 + n2];
  }
}

// ---- fused Q/K/V/Gate GEMM: BM=256, BN=128, 512 threads, XCD-banded (R17-proven) ----
__global__ __launch_bounds__(512, 4) void qkvg_gemm(
    const __bf16* __restrict__ xn, const __bf16* __restrict__ Wt,
    const float* __restrict__ bq, const float* __restrict__ bk,
    const float* __restrict__ bv, const float* __restrict__ bg,
    __bf16* __restrict__ qb, __bf16* __restrict__ kb,
    __bf16* __restrict__ vb, __bf16* __restrict__ gateb)
{
  __shared__ alignas(16) __bf16 Al[256 * 64];   // 32 KB
  __shared__ alignas(16) __bf16 Bl[128 * 64];   // 16 KB
  const int t = threadIdx.x;
  const int wave = t >> 6, lane = t & 63;
  const int l15 = lane & 15, l16 = lane >> 4;
  const int bid = blockIdx.x;
  const int xcd = bid & 7, idx = bid >> 3;
  const int m0 = (xcd * 16 + (idx & 15)) * 256;
  const int bn = idx >> 4;
  const int w = bn >> 1;
  const int nloc0 = (bn & 1) * 128;
  const __bf16* Wtw = Wt + (size_t)w * 65536;
  const int wm = (wave >> 1) * 64, wn = (wave & 1) * 64;

  const int srow = (lane >> 3);
  const int chunk = ((lane & 7) ^ srow) * 8;

  f32x4 acc[4][4];
#pragma unroll
  for (int i = 0; i < 4; ++i)
#pragma unroll
    for (int j = 0; j < 4; ++j) acc[i][j] = (f32x4){0.f, 0.f, 0.f, 0.f};

  for (int kt = 0; kt < 4; ++kt) {
    const int k0 = kt * 64;
#pragma unroll
    for (int i = 0; i < 4; ++i) {
      const int row = (wave * 4 + i) * 8 + srow;
      GLOAD_LDS16(xn + (size_t)(m0 + row) * 256 + k0 + chunk, &Al[(wave * 4 + i) * 512]);
    }
#pragma unroll
    for (int i = 0; i < 2; ++i) {
      const int row = (wave * 2 + i) * 8 + srow;
      GLOAD_LDS16(Wtw + (size_t)(nloc0 + row) * 256 + k0 + chunk, &Bl[(wave * 2 + i) * 512]);
    }
    __syncthreads();
#pragma unroll
    for (int kk = 0; kk < 2; ++kk) {
      bf16x8 a[4], bfr[4];
#pragma unroll
      for (int mi = 0; mi < 4; ++mi) {
        const int row = wm + mi * 16 + l15;
        a[mi] = *(const bf16x8*)&Al[row * 64 + ((kk * 32 + l16 * 8) ^ ((row & 7) << 3))];
      }
#pragma unroll
      for (int ni = 0; ni < 4; ++ni) {
        const int row = wn + ni * 16 + l15;
        bfr[ni] = *(const bf16x8*)&Bl[row * 64 + ((kk * 32 + l16 * 8) ^ ((row & 7) << 3))];
      }
#pragma unroll
      for (int mi = 0; mi < 4; ++mi)
#pragma unroll
        for (int ni = 0; ni < 4; ++ni)
          acc[mi][ni] = __builtin_amdgcn_mfma_f32_16x16x32_bf16(a[mi], bfr[ni], acc[mi][ni], 0, 0, 0);
    }
    __syncthreads();
  }

  const float* bias_arr = (w == 0) ? bq : (w == 1) ? bk : (w == 2) ? bv : bg;
  float bnis[4];
#pragma unroll
  for (int ni = 0; ni < 4; ++ni) bnis[ni] = bias_arr[nloc0 + wn + ni * 16 + l15];
  const float qscale = 0.17677669529663687f * L2E;

#pragma unroll
  for (int mi = 0; mi < 4; ++mi)
#pragma unroll
    for (int ni = 0; ni < 4; ++ni)
#pragma unroll
      for (int r = 0; r < 4; ++r) {
        const int grow = m0 + wm + mi * 16 + l16 * 4 + r;
        const int gcol = nloc0 + wn + ni * 16 + l15;
        const float v = acc[mi][ni][r] + bnis[ni];
        const int n = grow >> 8, i2 = grow & 255, h = gcol >> 5, dh = gcol & 31;
        const size_t hoff = (((size_t)n * 8 + h) * 256 + i2) * 32 + dh;
        if (w == 0)      qb[hoff] = (__bf16)(v * qscale);
        else if (w == 1) kb[hoff] = (__bf16)v;
        else if (w == 2) vb[hoff] = (__bf16)v;
        else gateb[(size_t)grow * 256 + gcol] = (__bf16)(1.f / (1.f + __expf(-v)));
      }
}

// ---------------- flash attention: R17-exact (512 threads, (512,4), t<256 staging) ----------------
__device__ __forceinline__ unsigned pk2(float a, float b) {
  bf16x2 t; t[0] = (__bf16)a; t[1] = (__bf16)b;
  return __builtin_bit_cast(unsigned, t);
}

__global__ __launch_bounds__(512, 4) void attn_kernel(
    const __bf16* __restrict__ qb, const __bf16* __restrict__ kb,
    const __bf16* __restrict__ vb, const float* __restrict__ biasf,
    const int* __restrict__ mask, __bf16* __restrict__ opre)
{
  __shared__ alignas(16) __bf16 Kl[256 * KLS];  // K [key][dh], 20KB
  __shared__ alignas(16) __bf16 Vt[32 * VTS];   // V^T [dh][key], 16.9KB
  __shared__ alignas(16) float Ml[256];          // additive mask
  const int t = threadIdx.x, wave = t >> 6, lane = t & 63;
  const int l31 = lane & 31, hi = lane >> 5;
  const int nh = blockIdx.x;
  const int n = nh >> 3, h = nh & 7;
  const __bf16* qbh = qb + (size_t)nh * 8192;

  if (t < 256) { // stage K + V^T + mask — R13-exact pattern (0 bank conflicts)
    const bf16x8* ks = (const bf16x8*)(kb + (size_t)nh * 8192 + t * 32);
    bf16x8 kr[4];
#pragma unroll
    for (int j = 0; j < 4; ++j) kr[j] = ks[j];
#pragma unroll
    for (int j = 0; j < 4; ++j) *(bf16x8*)&Kl[t * KLS + j * 8] = kr[j];
    const bf16x8* vs = (const bf16x8*)(vb + (size_t)nh * 8192 + t * 32);
    bf16x8 vv[4];
#pragma unroll
    for (int j = 0; j < 4; ++j) vv[j] = vs[j];
#pragma unroll
    for (int j = 0; j < 4; ++j)
#pragma unroll
      for (int e = 0; e < 8; ++e) Vt[(j * 8 + e) * VTS + t] = vv[j][e];
    Ml[t] = mask[n * 256 + t] ? 0.f : -1e9f;
  }
  __syncthreads();

  const int q0 = wave * 32;           // 8 waves cover q = 0..255
  const int q = q0 + l31;
  const bf16x8 Qf0 = *(const bf16x8*)(qbh + (size_t)q * 32 + hi * 8);
  const bf16x8 Qf1 = *(const bf16x8*)(qbh + (size_t)q * 32 + 16 + hi * 8);

  const float* bp = biasf + (size_t)h * 65536 + (size_t)q * 256;

  // prefetch tile 0: (bias + mask) combined
  f32x4 bc[4];
#pragma unroll
  for (int g = 0; g < 4; ++g) {
    const f32x4 bv = *(const f32x4*)(bp + 8 * g + 4 * hi);
    const f32x4 mk = *(const f32x4*)&Ml[8 * g + 4 * hi];
    bc[g] = bv + mk;
  }

  f32x16 Ot;
#pragma unroll
  for (int r = 0; r < 16; ++r) Ot[r] = 0.f;
  float lrun = 0.f;

#pragma unroll 1
  for (int kt = 0; kt < 8; ++kt) {
    const int k0 = kt * 32;
    const int ktn = (kt + 1) & 7;
    const bf16x8 Kf0 = *(const bf16x8*)&Kl[(k0 + l31) * KLS + hi * 8];
    const bf16x8 Kf1 = *(const bf16x8*)&Kl[(k0 + l31) * KLS + 16 + hi * 8];
    const bf16x8 Vf0 = *(const bf16x8*)&Vt[l31 * VTS + k0 + hi * 8];
    const bf16x8 Vf1 = *(const bf16x8*)&Vt[l31 * VTS + k0 + 16 + hi * 8];
    f32x16 st;
#pragma unroll
    for (int g = 0; g < 4; ++g)
#pragma unroll
      for (int e = 0; e < 4; ++e) st[4 * g + e] = bc[g][e];
    st = __builtin_amdgcn_mfma_f32_32x32x16_bf16(Kf0, Qf0, st, 0, 0, 0);
    st = __builtin_amdgcn_mfma_f32_32x32x16_bf16(Kf1, Qf1, st, 0, 0, 0);
#pragma unroll
    for (int g = 0; g < 4; ++g) {
      const f32x4 bv = *(const f32x4*)(bp + ktn * 32 + 8 * g + 4 * hi);
      const f32x4 mk = *(const f32x4*)&Ml[ktn * 32 + 8 * g + 4 * hi];
      bc[g] = bv + mk;
    }
#pragma unroll
    for (int r = 0; r < 16; ++r) st[r] = exp2f(st[r]);
    float ts = st[0];
#pragma unroll
    for (int r = 1; r < 16; ++r) ts += st[r];
    SUM32(ts, lrun);
    unsigned c0 = pk2(st[0],  st[1]),  c1 = pk2(st[2],  st[3]);
    unsigned c2 = pk2(st[4],  st[5]),  c3 = pk2(st[6],  st[7]);
    unsigned c4 = pk2(st[8],  st[9]),  c5 = pk2(st[10], st[11]);
    unsigned c6 = pk2(st[12], st[13]), c7 = pk2(st[14], st[15]);
    SWP(c0, c2); SWP(c1, c3); SWP(c4, c6); SWP(c5, c7);
    u32x4 w0 = {c0, c1, c2, c3}, w1 = {c4, c5, c6, c7};
    const bf16x8 pf0 = __builtin_bit_cast(bf16x8, w0);
    const bf16x8 pf1 = __builtin_bit_cast(bf16x8, w1);
    Ot = __builtin_amdgcn_mfma_f32_32x32x16_bf16(Vf0, pf0, Ot, 0, 0, 0);
    Ot = __builtin_amdgcn_mfma_f32_32x32x16_bf16(Vf1, pf1, Ot, 0, 0, 0);
  }

  // ---- epilogue: opre h-major [h][n][q][dh], permlane exchange, 2x16B stores ----
  const float invl = 1.f / lrun;
  unsigned P00 = pk2(Ot[0]  * invl, Ot[1]  * invl), P01 = pk2(Ot[2]  * invl, Ot[3]  * invl);
  unsigned P10 = pk2(Ot[4]  * invl, Ot[5]  * invl), P11 = pk2(Ot[6]  * invl, Ot[7]  * invl);
  unsigned P20 = pk2(Ot[8]  * invl, Ot[9]  * invl), P21 = pk2(Ot[10] * invl, Ot[11] * invl);
  unsigned P30 = pk2(Ot[12] * invl, Ot[13] * invl), P31 = pk2(Ot[14] * invl, Ot[15] * invl);
  SWP(P00, P20); SWP(P01, P21); SWP(P10, P30); SWP(P11, P31);
  u32x4 s0 = {P00, P01, P20, P21}, s1 = {P10, P11, P30, P31};
  __bf16* dst = opre + (((size_t)h * 128 + n) * 256 + q) * 32 + hi * 16;
  *(u32x4*)dst = s0;
  *(u32x4*)(dst + 8) = s1;
}

// ---------------- output projection + gate, XCD-banded (memory-floor-bound) ----------------
__global__ __launch_bounds__(256) void wo_gemm(
    const __bf16* __restrict__ A, const __bf16* __restrict__ Wtw,
    const float* __restrict__ bo, const __bf16* __restrict__ gateb,
    float* __restrict__ out)
{
  __shared__ alignas(16) __bf16 Al[128 * 64];
  __shared__ alignas(16) __bf16 Bl[128 * 64];
  const int t = threadIdx.x;
  const int wave = t >> 6, lane = t & 63;
  const int l15 = lane & 15, l16 = lane >> 4;
  const int bid = blockIdx.x;
  const int xcd = bid & 7, idx = bid >> 3;
  const int m0 = (xcd * 32 + (idx & 31)) * 128;
  const int nloc0 = (idx >> 5) * 128;
  const int wm = (wave >> 1) * 64, wn = (wave & 1) * 64;

  const int srow = (lane >> 3);
  const int chunk = ((lane & 7) ^ srow) * 8;

  f32x4 acc[4][4];
#pragma unroll
  for (int i = 0; i < 4; ++i)
#pragma unroll
    for (int j = 0; j < 4; ++j) acc[i][j] = (f32x4){0.f, 0.f, 0.f, 0.f};

  for (int kt = 0; kt < 4; ++kt) {
    const int k0 = kt * 64;
#pragma unroll
    for (int i = 0; i < 4; ++i) {
      const int row = wave * 32 + i * 8 + srow;
      const int m = m0 + row;
      const int kg = k0 + chunk;
      GLOAD_LDS16(A + (size_t)(kg >> 5) * 1048576 + (size_t)(m >> 8) * 8192
                    + (m & 255) * 32 + (kg & 31),
                  &Al[(wave * 4 + i) * 512]);
      GLOAD_LDS16(Wtw + (size_t)(nloc0 + row) * 256 + kg, &Bl[(wave * 4 + i) * 512]);
    }
    __syncthreads();
#pragma unroll
    for (int kk = 0; kk < 2; ++kk) {
      bf16x8 a[4], bfr[4];
#pragma unroll
      for (int mi = 0; mi < 4; ++mi) {
        const int row = wm + mi * 16 + l15;
        a[mi] = *(const bf16x8*)&Al[row * 64 + ((kk * 32 + l16 * 8) ^ ((row & 7) << 3))];
      }
#pragma unroll
      for (int ni = 0; ni < 4; ++ni) {
        const int row = wn + ni * 16 + l15;
        bfr[ni] = *(const bf16x8*)&Bl[row * 64 + ((kk * 32 + l16 * 8) ^ ((row & 7) << 3))];
      }
#pragma unroll
      for (int mi = 0; mi < 4; ++mi)
#pragma unroll
        for (int ni = 0; ni < 4; ++ni)
          acc[mi][ni] = __builtin_amdgcn_mfma_f32_16x16x32_bf16(a[mi], bfr[ni], acc[mi][ni], 0, 0, 0);
    }
    __syncthreads();
  }

  float bov[4];
#pragma unroll
  for (int ni = 0; ni < 4; ++ni) bov[ni] = bo[nloc0 + wn + ni * 16 + l15];
#pragma unroll
  for (int mi = 0; mi < 4; ++mi)
#pragma unroll
    for (int ni = 0; ni < 4; ++ni)
#pragma unroll
      for (int r = 0; r < 4; ++r) {
        const int grow = m0 + wm + mi * 16 + l16 * 4 + r;
        const int gcol = nloc0 + wn + ni * 16 + l15;
        const size_t o = (size_t)grow * 256 + gcol;
        out[o] = (acc[mi][ni][r] + bov[ni]) * (float)gateb[o];
      }
}

extern "C" void kernel_launch(void* const* d_in, const int* in_sizes, int n_in,
                              void* d_out, int out_size, void* d_ws, size_t ws_size,
                              hipStream_t stream)
{
  const float* msa  = (const float*)d_in[0];
  const float* pair = (const float*)d_in[1];
  const int*   mask = (const int*)d_in[2];
  const float* ln_g = (const float*)d_in[3];
  const float* ln_b = (const float*)d_in[4];
  const float* Wq = (const float*)d_in[5];  const float* bq = (const float*)d_in[6];
  const float* Wk = (const float*)d_in[7];  const float* bk = (const float*)d_in[8];
  const float* Wv = (const float*)d_in[9];  const float* bv = (const float*)d_in[10];
  const float* Wb = (const float*)d_in[11]; const float* bb = (const float*)d_in[12];
  const float* Wo = (const float*)d_in[13]; const float* bo = (const float*)d_in[14];
  const float* Wg = (const float*)d_in[15]; const float* bg = (const float*)d_in[16];
  float* out = (float*)d_out;

  char* ws = (char*)d_ws;
  __bf16* xn    = (__bf16*)(ws);
  __bf16* qb    = (__bf16*)(ws + 16777216);
  __bf16* kb    = (__bf16*)(ws + 2 * 16777216);
  __bf16* vb    = (__bf16*)(ws + 3 * 16777216);
  __bf16* opre  = (__bf16*)(ws + 4 * 16777216);
  __bf16* Wt    = (__bf16*)(ws + 5 * 16777216);                      // 640KB
  __bf16* gateb = (__bf16*)(ws + 5 * 16777216 + 655360);             // 16.8MB
  float*  biasf = (float*)(ws + 5 * 16777216 + 655360 + 16777216);   // 2MB [h][q][k]

  hipLaunchKernelGGL(setup_kernel, dim3(9728), dim3(256), 0, stream,
                     msa, ln_g, ln_b, xn, pair, Wb, bb, biasf, Wq, Wk, Wv, Wg, Wo, Wt);
  hipLaunchKernelGGL(qkvg_gemm,   dim3(1024), dim3(512), 0, stream, xn, Wt, bq, bk, bv, bg, qb, kb, vb, gateb);
  hipLaunchKernelGGL(attn_kernel, dim3(1024), dim3(512), 0, stream, qb, kb, vb, biasf, mask, opre);
  hipLaunchKernelGGL(wo_gemm,     dim3(512),  dim3(256), 0, stream, opre, Wt + 4 * 65536, bo, gateb, out);
}

// Round 20
// 114.254 us; speedup vs baseline: 1.1425x; 1.1091x over previous
//
#include <hip/hip_runtime.h>
#include <hip/hip_bf16.h>

typedef __attribute__((ext_vector_type(4))) float f32x4;
typedef __attribute__((ext_vector_type(16))) float f32x16;
typedef __attribute__((ext_vector_type(8))) __bf16 bf16x8;
typedef __attribute__((ext_vector_type(4))) __bf16 bf16x4;
typedef __attribute__((ext_vector_type(2))) __bf16 bf16x2;
typedef __attribute__((ext_vector_type(4))) unsigned u32x4;
typedef __attribute__((ext_vector_type(2))) unsigned u32x2;

#define VTS 264  // attn V^T LDS stride
#define KLS 40   // attn K LDS stride (80B rows, 16B-aligned)
#define L2E 1.4426950408889634f

#define GLOAD_LDS16(g, l) __builtin_amdgcn_global_load_lds( \
    (const __attribute__((address_space(1))) void*)(g),     \
    (__attribute__((address_space(3))) void*)(l), 16, 0, 0)

// exchange: a' = (a_lo, b_lo) ; b' = (a_hi, b_hi). Operands MUST be distinct
// values (HW RMWs two registers; self-aliased operands corrupt — R7-R9 bug).
#if __has_builtin(__builtin_amdgcn_permlane32_swap)
#define SWP(a, b) { u32x2 _r = __builtin_amdgcn_permlane32_swap((a), (b), false, false); \
                    (a) = _r[0]; (b) = _r[1]; }
#else
#define SWP(a, b) { unsigned _sa = __shfl_xor((a), 32), _sb = __shfl_xor((b), 32); \
                    unsigned _na = hi ? _sb : (a); (b) = hi ? (b) : _sa; (a) = _na; }
#endif
#define SUM32(ts, lrun) { (lrun) += (ts) + __shfl_xor((ts), 32); }

// ---------------- merged setup: ln (0..8191) | bias (8192..8447) | prep (8448..9727) ----------------
// bias layout: biasP[h][kt][g][hi][q][e], k = kt*32 + 8g + 4hi + e  (matches MFMA C rows;
// attn lanes (q = lane&31) read CONTIGUOUS 512B per wave instruction — no L2 gather)
__global__ __launch_bounds__(256) void setup_kernel(
    const float* __restrict__ msa, const float* __restrict__ g,
    const float* __restrict__ b, __bf16* __restrict__ xn,
    const float* __restrict__ pair, const float* __restrict__ Wb,
    const float* __restrict__ bb, float* __restrict__ biasP,
    const float* __restrict__ Wq, const float* __restrict__ Wk,
    const float* __restrict__ Wv, const float* __restrict__ Wg,
    const float* __restrict__ Wo, __bf16* __restrict__ Wt)
{
  __shared__ float wbs[1024];
  const int bid = blockIdx.x;
  const int t = threadIdx.x;
  if (bid < 8192) {
    const int row = bid * 4 + (t >> 6);
    const int lane = t & 63;
    f32x4 x = *(const f32x4*)(msa + (size_t)row * 256 + lane * 4);
    float s = x[0] + x[1] + x[2] + x[3];
    float s2 = x[0]*x[0] + x[1]*x[1] + x[2]*x[2] + x[3]*x[3];
#pragma unroll
    for (int d = 32; d >= 1; d >>= 1) {
      s  += __shfl_xor(s, d);
      s2 += __shfl_xor(s2, d);
    }
    const float mu  = s * (1.f / 256.f);
    const float inv = rsqrtf(s2 * (1.f / 256.f) - mu * mu + 1e-5f);
    const f32x4 gv = *(const f32x4*)(g + lane * 4);
    const f32x4 bv = *(const f32x4*)(b + lane * 4);
    bf16x4 o;
#pragma unroll
    for (int j = 0; j < 4; ++j) o[j] = (__bf16)((x[j] - mu) * inv * gv[j] + bv[j]);
    *(bf16x4*)(xn + (size_t)row * 256 + lane * 4) = o;
  } else if (bid < 8448) {
#pragma unroll
    for (int r2 = 0; r2 < 4; ++r2) wbs[t + 256 * r2] = Wb[t + 256 * r2];
    __syncthreads();
    const int i = bid - 8192, j = t;   // i = q row, j = key
    const float* src = pair + ((size_t)i * 256 + j) * 128;
    float acc[8];
#pragma unroll
    for (int hh = 0; hh < 8; ++hh) acc[hh] = bb[hh];
    for (int p = 0; p < 128; p += 4) {
      const f32x4 pv = *(const f32x4*)(src + p);
#pragma unroll
      for (int q2 = 0; q2 < 4; ++q2)
#pragma unroll
        for (int hh = 0; hh < 8; ++hh) acc[hh] += pv[q2] * wbs[(p + q2) * 8 + hh];
    }
    const int kt2 = j >> 5, g2 = (j >> 3) & 3, h2 = (j >> 2) & 1, e2 = j & 3;
#pragma unroll
    for (int hh = 0; hh < 8; ++hh)
      biasP[(((((size_t)hh * 8 + kt2) * 4 + g2) * 2 + h2) * 256 + i) * 4 + e2] =
          acc[hh] * L2E;
  } else {
    const int idx = bid - 8448;
    const int w = idx >> 8, n2 = idx & 255, k = t;
    const float* W = (w == 0) ? Wq : (w == 1) ? Wk : (w == 2) ? Wv : (w == 3) ? Wg : Wo;
    Wt[((size_t)w * 256 + n2) * 256 + k] = (__bf16)W[(size_t)k * 256 + n2];
  }
}

// ---- fused Q/K/V/Gate GEMM: BM=256, BN=128, 512 threads, XCD-banded (R17-proven) ----
__global__ __launch_bounds__(512, 4) void qkvg_gemm(
    const __bf16* __restrict__ xn, const __bf16* __restrict__ Wt,
    const float* __restrict__ bq, const float* __restrict__ bk,
    const float* __restrict__ bv, const float* __restrict__ bg,
    __bf16* __restrict__ qb, __bf16* __restrict__ kb,
    __bf16* __restrict__ vb, __bf16* __restrict__ gateb)
{
  __shared__ alignas(16) __bf16 Al[256 * 64];   // 32 KB
  __shared__ alignas(16) __bf16 Bl[128 * 64];   // 16 KB
  const int t = threadIdx.x;
  const int wave = t >> 6, lane = t & 63;
  const int l15 = lane & 15, l16 = lane >> 4;
  const int bid = blockIdx.x;
  const int xcd = bid & 7, idx = bid >> 3;
  const int m0 = (xcd * 16 + (idx & 15)) * 256;
  const int bn = idx >> 4;
  const int w = bn >> 1;
  const int nloc0 = (bn & 1) * 128;
  const __bf16* Wtw = Wt + (size_t)w * 65536;
  const int wm = (wave >> 1) * 64, wn = (wave & 1) * 64;

  const int srow = (lane >> 3);
  const int chunk = ((lane & 7) ^ srow) * 8;

  f32x4 acc[4][4];
#pragma unroll
  for (int i = 0; i < 4; ++i)
#pragma unroll
    for (int j = 0; j < 4; ++j) acc[i][j] = (f32x4){0.f, 0.f, 0.f, 0.f};

  for (int kt = 0; kt < 4; ++kt) {
    const int k0 = kt * 64;
#pragma unroll
    for (int i = 0; i < 4; ++i) {
      const int row = (wave * 4 + i) * 8 + srow;
      GLOAD_LDS16(xn + (size_t)(m0 + row) * 256 + k0 + chunk, &Al[(wave * 4 + i) * 512]);
    }
#pragma unroll
    for (int i = 0; i < 2; ++i) {
      const int row = (wave * 2 + i) * 8 + srow;
      GLOAD_LDS16(Wtw + (size_t)(nloc0 + row) * 256 + k0 + chunk, &Bl[(wave * 2 + i) * 512]);
    }
    __syncthreads();
#pragma unroll
    for (int kk = 0; kk < 2; ++kk) {
      bf16x8 a[4], bfr[4];
#pragma unroll
      for (int mi = 0; mi < 4; ++mi) {
        const int row = wm + mi * 16 + l15;
        a[mi] = *(const bf16x8*)&Al[row * 64 + ((kk * 32 + l16 * 8) ^ ((row & 7) << 3))];
      }
#pragma unroll
      for (int ni = 0; ni < 4; ++ni) {
        const int row = wn + ni * 16 + l15;
        bfr[ni] = *(const bf16x8*)&Bl[row * 64 + ((kk * 32 + l16 * 8) ^ ((row & 7) << 3))];
      }
#pragma unroll
      for (int mi = 0; mi < 4; ++mi)
#pragma unroll
        for (int ni = 0; ni < 4; ++ni)
          acc[mi][ni] = __builtin_amdgcn_mfma_f32_16x16x32_bf16(a[mi], bfr[ni], acc[mi][ni], 0, 0, 0);
    }
    __syncthreads();
  }

  const float* bias_arr = (w == 0) ? bq : (w == 1) ? bk : (w == 2) ? bv : bg;
  float bnis[4];
#pragma unroll
  for (int ni = 0; ni < 4; ++ni) bnis[ni] = bias_arr[nloc0 + wn + ni * 16 + l15];
  const float qscale = 0.17677669529663687f * L2E;

#pragma unroll
  for (int mi = 0; mi < 4; ++mi)
#pragma unroll
    for (int ni = 0; ni < 4; ++ni)
#pragma unroll
      for (int r = 0; r < 4; ++r) {
        const int grow = m0 + wm + mi * 16 + l16 * 4 + r;
        const int gcol = nloc0 + wn + ni * 16 + l15;
        const float v = acc[mi][ni][r] + bnis[ni];
        const int n = grow >> 8, i2 = grow & 255, h = gcol >> 5, dh = gcol & 31;
        const size_t hoff = (((size_t)n * 8 + h) * 256 + i2) * 32 + dh;
        if (w == 0)      qb[hoff] = (__bf16)(v * qscale);
        else if (w == 1) kb[hoff] = (__bf16)v;
        else if (w == 2) vb[hoff] = (__bf16)v;
        else gateb[(size_t)grow * 256 + gcol] = (__bf16)(1.f / (1.f + __expf(-v)));
      }
}

// ---------------- flash attention: R17 structure + coalesced packed bias ----------------
__device__ __forceinline__ unsigned pk2(float a, float b) {
  bf16x2 t; t[0] = (__bf16)a; t[1] = (__bf16)b;
  return __builtin_bit_cast(unsigned, t);
}

__global__ __launch_bounds__(512, 4) void attn_kernel(
    const __bf16* __restrict__ qb, const __bf16* __restrict__ kb,
    const __bf16* __restrict__ vb, const float* __restrict__ biasP,
    const int* __restrict__ mask, __bf16* __restrict__ opre)
{
  __shared__ alignas(16) __bf16 Kl[256 * KLS];  // K [key][dh], 20KB
  __shared__ alignas(16) __bf16 Vt[32 * VTS];   // V^T [dh][key], 16.9KB
  __shared__ alignas(16) float Ml[256];          // additive mask
  const int t = threadIdx.x, wave = t >> 6, lane = t & 63;
  const int l31 = lane & 31, hi = lane >> 5;
  const int nh = blockIdx.x;
  const int n = nh >> 3, h = nh & 7;
  const __bf16* qbh = qb + (size_t)nh * 8192;

  if (t < 256) { // stage K + V^T + mask — R13-exact pattern (0 bank conflicts)
    const bf16x8* ks = (const bf16x8*)(kb + (size_t)nh * 8192 + t * 32);
    bf16x8 kr[4];
#pragma unroll
    for (int j = 0; j < 4; ++j) kr[j] = ks[j];
#pragma unroll
    for (int j = 0; j < 4; ++j) *(bf16x8*)&Kl[t * KLS + j * 8] = kr[j];
    const bf16x8* vs = (const bf16x8*)(vb + (size_t)nh * 8192 + t * 32);
    bf16x8 vv[4];
#pragma unroll
    for (int j = 0; j < 4; ++j) vv[j] = vs[j];
#pragma unroll
    for (int j = 0; j < 4; ++j)
#pragma unroll
      for (int e = 0; e < 8; ++e) Vt[(j * 8 + e) * VTS + t] = vv[j][e];
    Ml[t] = mask[n * 256 + t] ? 0.f : -1e9f;
  }
  __syncthreads();

  const int q0 = wave * 32;           // 8 waves cover q = 0..255
  const int q = q0 + l31;
  const bf16x8 Qf0 = *(const bf16x8*)(qbh + (size_t)q * 32 + hi * 8);
  const bf16x8 Qf1 = *(const bf16x8*)(qbh + (size_t)q * 32 + 16 + hi * 8);

  // packed bias base for this head: biasP[h][kt][g][hi][q][e]
  const float* bph = biasP + (size_t)h * 65536;

  // prefetch tile 0: (bias + mask) combined  [coalesced: lanes read consecutive 16B]
  f32x4 bc[4];
#pragma unroll
  for (int g = 0; g < 4; ++g) {
    const f32x4 bv = *(const f32x4*)(bph + ((g * 2 + hi) * 256 + q) * 4);
    const f32x4 mk = *(const f32x4*)&Ml[8 * g + 4 * hi];
    bc[g] = bv + mk;
  }

  f32x16 Ot;
#pragma unroll
  for (int r = 0; r < 16; ++r) Ot[r] = 0.f;
  float lrun = 0.f;

#pragma unroll 1
  for (int kt = 0; kt < 8; ++kt) {
    const int k0 = kt * 32;
    const int ktn = (kt + 1) & 7;
    const bf16x8 Kf0 = *(const bf16x8*)&Kl[(k0 + l31) * KLS + hi * 8];
    const bf16x8 Kf1 = *(const bf16x8*)&Kl[(k0 + l31) * KLS + 16 + hi * 8];
    const bf16x8 Vf0 = *(const bf16x8*)&Vt[l31 * VTS + k0 + hi * 8];
    const bf16x8 Vf1 = *(const bf16x8*)&Vt[l31 * VTS + k0 + 16 + hi * 8];
    f32x16 st;
#pragma unroll
    for (int g = 0; g < 4; ++g)
#pragma unroll
      for (int e = 0; e < 4; ++e) st[4 * g + e] = bc[g][e];
    st = __builtin_amdgcn_mfma_f32_32x32x16_bf16(Kf0, Qf0, st, 0, 0, 0);
    st = __builtin_amdgcn_mfma_f32_32x32x16_bf16(Kf1, Qf1, st, 0, 0, 0);
    // prefetch next tile's bias+mask (coalesced)
#pragma unroll
    for (int g = 0; g < 4; ++g) {
      const f32x4 bv = *(const f32x4*)(bph + (((ktn * 4 + g) * 2 + hi) * 256 + q) * 4);
      const f32x4 mk = *(const f32x4*)&Ml[ktn * 32 + 8 * g + 4 * hi];
      bc[g] = bv + mk;
    }
#pragma unroll
    for (int r = 0; r < 16; ++r) st[r] = exp2f(st[r]);
    float ts = st[0];
#pragma unroll
    for (int r = 1; r < 16; ++r) ts += st[r];
    SUM32(ts, lrun);
    unsigned c0 = pk2(st[0],  st[1]),  c1 = pk2(st[2],  st[3]);
    unsigned c2 = pk2(st[4],  st[5]),  c3 = pk2(st[6],  st[7]);
    unsigned c4 = pk2(st[8],  st[9]),  c5 = pk2(st[10], st[11]);
    unsigned c6 = pk2(st[12], st[13]), c7 = pk2(st[14], st[15]);
    SWP(c0, c2); SWP(c1, c3); SWP(c4, c6); SWP(c5, c7);
    u32x4 w0 = {c0, c1, c2, c3}, w1 = {c4, c5, c6, c7};
    const bf16x8 pf0 = __builtin_bit_cast(bf16x8, w0);
    const bf16x8 pf1 = __builtin_bit_cast(bf16x8, w1);
    Ot = __builtin_amdgcn_mfma_f32_32x32x16_bf16(Vf0, pf0, Ot, 0, 0, 0);
    Ot = __builtin_amdgcn_mfma_f32_32x32x16_bf16(Vf1, pf1, Ot, 0, 0, 0);
  }

  // ---- epilogue: opre h-major [h][n][q][dh], permlane exchange, 2x16B stores ----
  const float invl = 1.f / lrun;
  unsigned P00 = pk2(Ot[0]  * invl, Ot[1]  * invl), P01 = pk2(Ot[2]  * invl, Ot[3]  * invl);
  unsigned P10 = pk2(Ot[4]  * invl, Ot[5]  * invl), P11 = pk2(Ot[6]  * invl, Ot[7]  * invl);
  unsigned P20 = pk2(Ot[8]  * invl, Ot[9]  * invl), P21 = pk2(Ot[10] * invl, Ot[11] * invl);
  unsigned P30 = pk2(Ot[12] * invl, Ot[13] * invl), P31 = pk2(Ot[14] * invl, Ot[15] * invl);
  SWP(P00, P20); SWP(P01, P21); SWP(P10, P30); SWP(P11, P31);
  u32x4 s0 = {P00, P01, P20, P21}, s1 = {P10, P11, P30, P31};
  __bf16* dst = opre + (((size_t)h * 128 + n) * 256 + q) * 32 + hi * 16;
  *(u32x4*)dst = s0;
  *(u32x4*)(dst + 8) = s1;
}

// ---------------- output projection + gate, XCD-banded (memory-floor-bound) ----------------
__global__ __launch_bounds__(256) void wo_gemm(
    const __bf16* __restrict__ A, const __bf16* __restrict__ Wtw,
    const float* __restrict__ bo, const __bf16* __restrict__ gateb,
    float* __restrict__ out)
{
  __shared__ alignas(16) __bf16 Al[128 * 64];
  __shared__ alignas(16) __bf16 Bl[128 * 64];
  const int t = threadIdx.x;
  const int wave = t >> 6, lane = t & 63;
  const int l15 = lane & 15, l16 = lane >> 4;
  const int bid = blockIdx.x;
  const int xcd = bid & 7, idx = bid >> 3;
  const int m0 = (xcd * 32 + (idx & 31)) * 128;
  const int nloc0 = (idx >> 5) * 128;
  const int wm = (wave >> 1) * 64, wn = (wave & 1) * 64;

  const int srow = (lane >> 3);
  const int chunk = ((lane & 7) ^ srow) * 8;

  f32x4 acc[4][4];
#pragma unroll
  for (int i = 0; i < 4; ++i)
#pragma unroll
    for (int j = 0; j < 4; ++j) acc[i][j] = (f32x4){0.f, 0.f, 0.f, 0.f};

  for (int kt = 0; kt < 4; ++kt) {
    const int k0 = kt * 64;
#pragma unroll
    for (int i = 0; i < 4; ++i) {
      const int row = wave * 32 + i * 8 + srow;
      const int m = m0 + row;
      const int kg = k0 + chunk;
      GLOAD_LDS16(A + (size_t)(kg >> 5) * 1048576 + (size_t)(m >> 8) * 8192
                    + (m & 255) * 32 + (kg & 31),
                  &Al[(wave * 4 + i) * 512]);
      GLOAD_LDS16(Wtw + (size_t)(nloc0 + row) * 256 + kg, &Bl[(wave * 4 + i) * 512]);
    }
    __syncthreads();
#pragma unroll
    for (int kk = 0; kk < 2; ++kk) {
      bf16x8 a[4], bfr[4];
#pragma unroll
      for (int mi = 0; mi < 4; ++mi) {
        const int row = wm + mi * 16 + l15;
        a[mi] = *(const bf16x8*)&Al[row * 64 + ((kk * 32 + l16 * 8) ^ ((row & 7) << 3))];
      }
#pragma unroll
      for (int ni = 0; ni < 4; ++ni) {
        const int row = wn + ni * 16 + l15;
        bfr[ni] = *(const bf16x8*)&Bl[row * 64 + ((kk * 32 + l16 * 8) ^ ((row & 7) << 3))];
      }
#pragma unroll
      for (int mi = 0; mi < 4; ++mi)
#pragma unroll
        for (int ni = 0; ni < 4; ++ni)
          acc[mi][ni] = __builtin_amdgcn_mfma_f32_16x16x32_bf16(a[mi], bfr[ni], acc[mi][ni], 0, 0, 0);
    }
    __syncthreads();
  }

  float bov[4];
#pragma unroll
  for (int ni = 0; ni < 4; ++ni) bov[ni] = bo[nloc0 + wn + ni * 16 + l15];
#pragma unroll
  for (int mi = 0; mi < 4; ++mi)
#pragma unroll
    for (int ni = 0; ni < 4; ++ni)
#pragma unroll
      for (int r = 0; r < 4; ++r) {
        const int grow = m0 + wm + mi * 16 + l16 * 4 + r;
        const int gcol = nloc0 + wn + ni * 16 + l15;
        const size_t o = (size_t)grow * 256 + gcol;
        out[o] = (acc[mi][ni][r] + bov[ni]) * (float)gateb[o];
      }
}

extern "C" void kernel_launch(void* const* d_in, const int* in_sizes, int n_in,
                              void* d_out, int out_size, void* d_ws, size_t ws_size,
                              hipStream_t stream)
{
  const float* msa  = (const float*)d_in[0];
  const float* pair = (const float*)d_in[1];
  const int*   mask = (const int*)d_in[2];
  const float* ln_g = (const float*)d_in[3];
  const float* ln_b = (const float*)d_in[4];
  const float* Wq = (const float*)d_in[5];  const float* bq = (const float*)d_in[6];
  const float* Wk = (const float*)d_in[7];  const float* bk = (const float*)d_in[8];
  const float* Wv = (const float*)d_in[9];  const float* bv = (const float*)d_in[10];
  const float* Wb = (const float*)d_in[11]; const float* bb = (const float*)d_in[12];
  const float* Wo = (const float*)d_in[13]; const float* bo = (const float*)d_in[14];
  const float* Wg = (const float*)d_in[15]; const float* bg = (const float*)d_in[16];
  float* out = (float*)d_out;

  char* ws = (char*)d_ws;
  __bf16* xn    = (__bf16*)(ws);
  __bf16* qb    = (__bf16*)(ws + 16777216);
  __bf16* kb    = (__bf16*)(ws + 2 * 16777216);
  __bf16* vb    = (__bf16*)(ws + 3 * 16777216);
  __bf16* opre  = (__bf16*)(ws + 4 * 16777216);
  __bf16* Wt    = (__bf16*)(ws + 5 * 16777216);                      // 640KB
  __bf16* gateb = (__bf16*)(ws + 5 * 16777216 + 655360);             // 16.8MB
  float*  biasP = (float*)(ws + 5 * 16777216 + 655360 + 16777216);   // 2MB packed

  hipLaunchKernelGGL(setup_kernel, dim3(9728), dim3(256), 0, stream,
                     msa, ln_g, ln_b, xn, pair, Wb, bb, biasP, Wq, Wk, Wv, Wg, Wo, Wt);
  hipLaunchKernelGGL(qkvg_gemm,   dim3(1024), dim3(512), 0, stream, xn, Wt, bq, bk, bv, bg, qb, kb, vb, gateb);
  hipLaunchKernelGGL(attn_kernel, dim3(1024), dim3(512), 0, stream, qb, kb, vb, biasP, mask, opre);
  hipLaunchKernelGGL(wo_gemm,     dim3(512),  dim3(256), 0, stream, opre, Wt + 4 * 65536, bo, gateb, out);
}

// Round 21
// 112.314 us; speedup vs baseline: 1.1622x; 1.0173x over previous
//
#include <hip/hip_runtime.h>
#include <hip/hip_bf16.h>

typedef __attribute__((ext_vector_type(4))) float f32x4;
typedef __attribute__((ext_vector_type(16))) float f32x16;
typedef __attribute__((ext_vector_type(8))) __bf16 bf16x8;
typedef __attribute__((ext_vector_type(4))) __bf16 bf16x4;
typedef __attribute__((ext_vector_type(2))) __bf16 bf16x2;
typedef __attribute__((ext_vector_type(4))) unsigned u32x4;
typedef __attribute__((ext_vector_type(2))) unsigned u32x2;

#define VTS 264  // attn V^T LDS stride
#define KLS 40   // attn K LDS stride (80B rows, 16B-aligned)
#define L2E 1.4426950408889634f

#define GLOAD_LDS16(g, l) __builtin_amdgcn_global_load_lds( \
    (const __attribute__((address_space(1))) void*)(g),     \
    (__attribute__((address_space(3))) void*)(l), 16, 0, 0)

// exchange: a' = (a_lo, b_lo) ; b' = (a_hi, b_hi). Operands MUST be distinct
// values (HW RMWs two registers; self-aliased operands corrupt — R7-R9 bug).
#if __has_builtin(__builtin_amdgcn_permlane32_swap)
#define SWP(a, b) { u32x2 _r = __builtin_amdgcn_permlane32_swap((a), (b), false, false); \
                    (a) = _r[0]; (b) = _r[1]; }
#else
#define SWP(a, b) { unsigned _sa = __shfl_xor((a), 32), _sb = __shfl_xor((b), 32); \
                    unsigned _na = hi ? _sb : (a); (b) = hi ? (b) : _sa; (a) = _na; }
#endif
#define SUM32(ts, lrun) { (lrun) += (ts) + __shfl_xor((ts), 32); }

// ---- merged setup: ln (0..8191) | bias-GEMM (8192..10239) | prep (10240..11519) ----
// bias layout: biasP[h][kt][g][hi][q][e], k = kt*32 + 8g + 4hi + e  (MFMA-C rows;
// attn lanes (q = lane&31) read CONTIGUOUS 512B per wave instruction)
__global__ __launch_bounds__(256) void setup_kernel(
    const float* __restrict__ msa, const float* __restrict__ g,
    const float* __restrict__ b, __bf16* __restrict__ xn,
    const float* __restrict__ pair, const float* __restrict__ Wb,
    const float* __restrict__ bb, float* __restrict__ biasP,
    const float* __restrict__ Wq, const float* __restrict__ Wk,
    const float* __restrict__ Wv, const float* __restrict__ Wg,
    const float* __restrict__ Wo, __bf16* __restrict__ Wt)
{
  __shared__ float wbs[1024];
  const int bid = blockIdx.x;
  const int t = threadIdx.x;
  if (bid < 8192) {
    // ---- LayerNorm -> bf16 ----
    const int row = bid * 4 + (t >> 6);
    const int lane = t & 63;
    f32x4 x = *(const f32x4*)(msa + (size_t)row * 256 + lane * 4);
    float s = x[0] + x[1] + x[2] + x[3];
    float s2 = x[0]*x[0] + x[1]*x[1] + x[2]*x[2] + x[3]*x[3];
#pragma unroll
    for (int d = 32; d >= 1; d >>= 1) {
      s  += __shfl_xor(s, d);
      s2 += __shfl_xor(s2, d);
    }
    const float mu  = s * (1.f / 256.f);
    const float inv = rsqrtf(s2 * (1.f / 256.f) - mu * mu + 1e-5f);
    const f32x4 gv = *(const f32x4*)(g + lane * 4);
    const f32x4 bv = *(const f32x4*)(b + lane * 4);
    bf16x4 o;
#pragma unroll
    for (int j = 0; j < 4; ++j) o[j] = (__bf16)((x[j] - mu) * inv * gv[j] + bv[j]);
    *(bf16x4*)(xn + (size_t)row * 256 + lane * 4) = o;
  } else if (bid < 10240) {
    // ---- bias as coalesced tall-skinny GEMM: 8 lanes per pair-row ----
#pragma unroll
    for (int r2 = 0; r2 < 4; ++r2) wbs[t + 256 * r2] = Wb[t + 256 * r2];
    __syncthreads();
    const int rb = (bid - 8192) * 32 + (t >> 3);   // flat row (i*256+j), 0..65535
    const int g8 = t & 7;
    const float* src = pair + (size_t)rb * 128 + g8 * 16;
    f32x4 pv[4];
#pragma unroll
    for (int c = 0; c < 4; ++c) pv[c] = *(const f32x4*)(src + c * 4);
    float acc[8];
#pragma unroll
    for (int hh = 0; hh < 8; ++hh) acc[hh] = 0.f;
#pragma unroll
    for (int c = 0; c < 4; ++c)
#pragma unroll
      for (int e = 0; e < 4; ++e) {
        const int p = g8 * 16 + c * 4 + e;
        const f32x4 w0 = *(const f32x4*)&wbs[p * 8];
        const f32x4 w1 = *(const f32x4*)&wbs[p * 8 + 4];
#pragma unroll
        for (int hh = 0; hh < 4; ++hh) {
          acc[hh]     += pv[c][e] * w0[hh];
          acc[4 + hh] += pv[c][e] * w1[hh];
        }
      }
#pragma unroll
    for (int d = 1; d <= 4; d <<= 1)
#pragma unroll
      for (int hh = 0; hh < 8; ++hh) acc[hh] += __shfl_xor(acc[hh], d);
    // lane g8 writes h = g8 for this row
    const int i = rb >> 8, j = rb & 255;
    const int kt2 = j >> 5, g2 = (j >> 3) & 3, h2 = (j >> 2) & 1, e2 = j & 3;
    biasP[(((((size_t)g8 * 8 + kt2) * 4 + g2) * 2 + h2) * 256 + i) * 4 + e2] =
        (acc[g8] + bb[g8]) * L2E;
  } else {
    // ---- weight prep: Wt[w][n][k] = W_w[k][n] ----
    const int idx = bid - 10240;
    const int w = idx >> 8, n2 = idx & 255, k = t;
    const float* W = (w == 0) ? Wq : (w == 1) ? Wk : (w == 2) ? Wv : (w == 3) ? Wg : Wo;
    Wt[((size_t)w * 256 + n2) * 256 + k] = (__bf16)W[(size_t)k * 256 + n2];
  }
}

// ---- fused Q/K/V/Gate GEMM: BM=256, BN=128, 512 threads, XCD-banded (R17-proven) ----
__global__ __launch_bounds__(512, 4) void qkvg_gemm(
    const __bf16* __restrict__ xn, const __bf16* __restrict__ Wt,
    const float* __restrict__ bq, const float* __restrict__ bk,
    const float* __restrict__ bv, const float* __restrict__ bg,
    __bf16* __restrict__ qb, __bf16* __restrict__ kb,
    __bf16* __restrict__ vb, __bf16* __restrict__ gateb)
{
  __shared__ alignas(16) __bf16 Al[256 * 64];   // 32 KB
  __shared__ alignas(16) __bf16 Bl[128 * 64];   // 16 KB
  const int t = threadIdx.x;
  const int wave = t >> 6, lane = t & 63;
  const int l15 = lane & 15, l16 = lane >> 4;
  const int bid = blockIdx.x;
  const int xcd = bid & 7, idx = bid >> 3;
  const int m0 = (xcd * 16 + (idx & 15)) * 256;
  const int bn = idx >> 4;
  const int w = bn >> 1;
  const int nloc0 = (bn & 1) * 128;
  const __bf16* Wtw = Wt + (size_t)w * 65536;
  const int wm = (wave >> 1) * 64, wn = (wave & 1) * 64;

  const int srow = (lane >> 3);
  const int chunk = ((lane & 7) ^ srow) * 8;

  f32x4 acc[4][4];
#pragma unroll
  for (int i = 0; i < 4; ++i)
#pragma unroll
    for (int j = 0; j < 4; ++j) acc[i][j] = (f32x4){0.f, 0.f, 0.f, 0.f};

  for (int kt = 0; kt < 4; ++kt) {
    const int k0 = kt * 64;
#pragma unroll
    for (int i = 0; i < 4; ++i) {
      const int row = (wave * 4 + i) * 8 + srow;
      GLOAD_LDS16(xn + (size_t)(m0 + row) * 256 + k0 + chunk, &Al[(wave * 4 + i) * 512]);
    }
#pragma unroll
    for (int i = 0; i < 2; ++i) {
      const int row = (wave * 2 + i) * 8 + srow;
      GLOAD_LDS16(Wtw + (size_t)(nloc0 + row) * 256 + k0 + chunk, &Bl[(wave * 2 + i) * 512]);
    }
    __syncthreads();
#pragma unroll
    for (int kk = 0; kk < 2; ++kk) {
      bf16x8 a[4], bfr[4];
#pragma unroll
      for (int mi = 0; mi < 4; ++mi) {
        const int row = wm + mi * 16 + l15;
        a[mi] = *(const bf16x8*)&Al[row * 64 + ((kk * 32 + l16 * 8) ^ ((row & 7) << 3))];
      }
#pragma unroll
      for (int ni = 0; ni < 4; ++ni) {
        const int row = wn + ni * 16 + l15;
        bfr[ni] = *(const bf16x8*)&Bl[row * 64 + ((kk * 32 + l16 * 8) ^ ((row & 7) << 3))];
      }
#pragma unroll
      for (int mi = 0; mi < 4; ++mi)
#pragma unroll
        for (int ni = 0; ni < 4; ++ni)
          acc[mi][ni] = __builtin_amdgcn_mfma_f32_16x16x32_bf16(a[mi], bfr[ni], acc[mi][ni], 0, 0, 0);
    }
    __syncthreads();
  }

  const float* bias_arr = (w == 0) ? bq : (w == 1) ? bk : (w == 2) ? bv : bg;
  float bnis[4];
#pragma unroll
  for (int ni = 0; ni < 4; ++ni) bnis[ni] = bias_arr[nloc0 + wn + ni * 16 + l15];
  const float qscale = 0.17677669529663687f * L2E;

#pragma unroll
  for (int mi = 0; mi < 4; ++mi)
#pragma unroll
    for (int ni = 0; ni < 4; ++ni)
#pragma unroll
      for (int r = 0; r < 4; ++r) {
        const int grow = m0 + wm + mi * 16 + l16 * 4 + r;
        const int gcol = nloc0 + wn + ni * 16 + l15;
        const float v = acc[mi][ni][r] + bnis[ni];
        const int n = grow >> 8, i2 = grow & 255, h = gcol >> 5, dh = gcol & 31;
        const size_t hoff = (((size_t)n * 8 + h) * 256 + i2) * 32 + dh;
        if (w == 0)      qb[hoff] = (__bf16)(v * qscale);
        else if (w == 1) kb[hoff] = (__bf16)v;
        else if (w == 2) vb[hoff] = (__bf16)v;
        else gateb[(size_t)grow * 256 + gcol] = (__bf16)(1.f / (1.f + __expf(-v)));
      }
}

// ---------------- flash attention: R20-exact (coalesced packed bias) ----------------
__device__ __forceinline__ unsigned pk2(float a, float b) {
  bf16x2 t; t[0] = (__bf16)a; t[1] = (__bf16)b;
  return __builtin_bit_cast(unsigned, t);
}

__global__ __launch_bounds__(512, 4) void attn_kernel(
    const __bf16* __restrict__ qb, const __bf16* __restrict__ kb,
    const __bf16* __restrict__ vb, const float* __restrict__ biasP,
    const int* __restrict__ mask, __bf16* __restrict__ opre)
{
  __shared__ alignas(16) __bf16 Kl[256 * KLS];  // K [key][dh], 20KB
  __shared__ alignas(16) __bf16 Vt[32 * VTS];   // V^T [dh][key], 16.9KB
  __shared__ alignas(16) float Ml[256];          // additive mask
  const int t = threadIdx.x, wave = t >> 6, lane = t & 63;
  const int l31 = lane & 31, hi = lane >> 5;
  const int nh = blockIdx.x;
  const int n = nh >> 3, h = nh & 7;
  const __bf16* qbh = qb + (size_t)nh * 8192;

  if (t < 256) { // stage K + V^T + mask — R13-exact pattern (0 bank conflicts)
    const bf16x8* ks = (const bf16x8*)(kb + (size_t)nh * 8192 + t * 32);
    bf16x8 kr[4];
#pragma unroll
    for (int j = 0; j < 4; ++j) kr[j] = ks[j];
#pragma unroll
    for (int j = 0; j < 4; ++j) *(bf16x8*)&Kl[t * KLS + j * 8] = kr[j];
    const bf16x8* vs = (const bf16x8*)(vb + (size_t)nh * 8192 + t * 32);
    bf16x8 vv[4];
#pragma unroll
    for (int j = 0; j < 4; ++j) vv[j] = vs[j];
#pragma unroll
    for (int j = 0; j < 4; ++j)
#pragma unroll
      for (int e = 0; e < 8; ++e) Vt[(j * 8 + e) * VTS + t] = vv[j][e];
    Ml[t] = mask[n * 256 + t] ? 0.f : -1e9f;
  }
  __syncthreads();

  const int q0 = wave * 32;           // 8 waves cover q = 0..255
  const int q = q0 + l31;
  const bf16x8 Qf0 = *(const bf16x8*)(qbh + (size_t)q * 32 + hi * 8);
  const bf16x8 Qf1 = *(const bf16x8*)(qbh + (size_t)q * 32 + 16 + hi * 8);

  // packed bias base for this head: biasP[h][kt][g][hi][q][e]
  const float* bph = biasP + (size_t)h * 65536;

  // prefetch tile 0: (bias + mask) combined  [coalesced: lanes read consecutive 16B]
  f32x4 bc[4];
#pragma unroll
  for (int g = 0; g < 4; ++g) {
    const f32x4 bv = *(const f32x4*)(bph + ((g * 2 + hi) * 256 + q) * 4);
    const f32x4 mk = *(const f32x4*)&Ml[8 * g + 4 * hi];
    bc[g] = bv + mk;
  }

  f32x16 Ot;
#pragma unroll
  for (int r = 0; r < 16; ++r) Ot[r] = 0.f;
  float lrun = 0.f;

#pragma unroll 1
  for (int kt = 0; kt < 8; ++kt) {
    const int k0 = kt * 32;
    const int ktn = (kt + 1) & 7;
    const bf16x8 Kf0 = *(const bf16x8*)&Kl[(k0 + l31) * KLS + hi * 8];
    const bf16x8 Kf1 = *(const bf16x8*)&Kl[(k0 + l31) * KLS + 16 + hi * 8];
    const bf16x8 Vf0 = *(const bf16x8*)&Vt[l31 * VTS + k0 + hi * 8];
    const bf16x8 Vf1 = *(const bf16x8*)&Vt[l31 * VTS + k0 + 16 + hi * 8];
    f32x16 st;
#pragma unroll
    for (int g = 0; g < 4; ++g)
#pragma unroll
      for (int e = 0; e < 4; ++e) st[4 * g + e] = bc[g][e];
    st = __builtin_amdgcn_mfma_f32_32x32x16_bf16(Kf0, Qf0, st, 0, 0, 0);
    st = __builtin_amdgcn_mfma_f32_32x32x16_bf16(Kf1, Qf1, st, 0, 0, 0);
    // prefetch next tile's bias+mask (coalesced)
#pragma unroll
    for (int g = 0; g < 4; ++g) {
      const f32x4 bv = *(const f32x4*)(bph + (((ktn * 4 + g) * 2 + hi) * 256 + q) * 4);
      const f32x4 mk = *(const f32x4*)&Ml[ktn * 32 + 8 * g + 4 * hi];
      bc[g] = bv + mk;
    }
#pragma unroll
    for (int r = 0; r < 16; ++r) st[r] = exp2f(st[r]);
    float ts = st[0];
#pragma unroll
    for (int r = 1; r < 16; ++r) ts += st[r];
    SUM32(ts, lrun);
    unsigned c0 = pk2(st[0],  st[1]),  c1 = pk2(st[2],  st[3]);
    unsigned c2 = pk2(st[4],  st[5]),  c3 = pk2(st[6],  st[7]);
    unsigned c4 = pk2(st[8],  st[9]),  c5 = pk2(st[10], st[11]);
    unsigned c6 = pk2(st[12], st[13]), c7 = pk2(st[14], st[15]);
    SWP(c0, c2); SWP(c1, c3); SWP(c4, c6); SWP(c5, c7);
    u32x4 w0 = {c0, c1, c2, c3}, w1 = {c4, c5, c6, c7};
    const bf16x8 pf0 = __builtin_bit_cast(bf16x8, w0);
    const bf16x8 pf1 = __builtin_bit_cast(bf16x8, w1);
    Ot = __builtin_amdgcn_mfma_f32_32x32x16_bf16(Vf0, pf0, Ot, 0, 0, 0);
    Ot = __builtin_amdgcn_mfma_f32_32x32x16_bf16(Vf1, pf1, Ot, 0, 0, 0);
  }

  // ---- epilogue: opre h-major [h][n][q][dh], permlane exchange, 2x16B stores ----
  const float invl = 1.f / lrun;
  unsigned P00 = pk2(Ot[0]  * invl, Ot[1]  * invl), P01 = pk2(Ot[2]  * invl, Ot[3]  * invl);
  unsigned P10 = pk2(Ot[4]  * invl, Ot[5]  * invl), P11 = pk2(Ot[6]  * invl, Ot[7]  * invl);
  unsigned P20 = pk2(Ot[8]  * invl, Ot[9]  * invl), P21 = pk2(Ot[10] * invl, Ot[11] * invl);
  unsigned P30 = pk2(Ot[12] * invl, Ot[13] * invl), P31 = pk2(Ot[14] * invl, Ot[15] * invl);
  SWP(P00, P20); SWP(P01, P21); SWP(P10, P30); SWP(P11, P31);
  u32x4 s0 = {P00, P01, P20, P21}, s1 = {P10, P11, P30, P31};
  __bf16* dst = opre + (((size_t)h * 128 + n) * 256 + q) * 32 + hi * 16;
  *(u32x4*)dst = s0;
  *(u32x4*)(dst + 8) = s1;
}

// ---------------- output projection + gate, XCD-banded (memory-floor-bound) ----------------
__global__ __launch_bounds__(256) void wo_gemm(
    const __bf16* __restrict__ A, const __bf16* __restrict__ Wtw,
    const float* __restrict__ bo, const __bf16* __restrict__ gateb,
    float* __restrict__ out)
{
  __shared__ alignas(16) __bf16 Al[128 * 64];
  __shared__ alignas(16) __bf16 Bl[128 * 64];
  const int t = threadIdx.x;
  const int wave = t >> 6, lane = t & 63;
  const int l15 = lane & 15, l16 = lane >> 4;
  const int bid = blockIdx.x;
  const int xcd = bid & 7, idx = bid >> 3;
  const int m0 = (xcd * 32 + (idx & 31)) * 128;
  const int nloc0 = (idx >> 5) * 128;
  const int wm = (wave >> 1) * 64, wn = (wave & 1) * 64;

  const int srow = (lane >> 3);
  const int chunk = ((lane & 7) ^ srow) * 8;

  f32x4 acc[4][4];
#pragma unroll
  for (int i = 0; i < 4; ++i)
#pragma unroll
    for (int j = 0; j < 4; ++j) acc[i][j] = (f32x4){0.f, 0.f, 0.f, 0.f};

  for (int kt = 0; kt < 4; ++kt) {
    const int k0 = kt * 64;
#pragma unroll
    for (int i = 0; i < 4; ++i) {
      const int row = wave * 32 + i * 8 + srow;
      const int m = m0 + row;
      const int kg = k0 + chunk;
      GLOAD_LDS16(A + (size_t)(kg >> 5) * 1048576 + (size_t)(m >> 8) * 8192
                    + (m & 255) * 32 + (kg & 31),
                  &Al[(wave * 4 + i) * 512]);
      GLOAD_LDS16(Wtw + (size_t)(nloc0 + row) * 256 + kg, &Bl[(wave * 4 + i) * 512]);
    }
    __syncthreads();
#pragma unroll
    for (int kk = 0; kk < 2; ++kk) {
      bf16x8 a[4], bfr[4];
#pragma unroll
      for (int mi = 0; mi < 4; ++mi) {
        const int row = wm + mi * 16 + l15;
        a[mi] = *(const bf16x8*)&Al[row * 64 + ((kk * 32 + l16 * 8) ^ ((row & 7) << 3))];
      }
#pragma unroll
      for (int ni = 0; ni < 4; ++ni) {
        const int row = wn + ni * 16 + l15;
        bfr[ni] = *(const bf16x8*)&Bl[row * 64 + ((kk * 32 + l16 * 8) ^ ((row & 7) << 3))];
      }
#pragma unroll
      for (int mi = 0; mi < 4; ++mi)
#pragma unroll
        for (int ni = 0; ni < 4; ++ni)
          acc[mi][ni] = __builtin_amdgcn_mfma_f32_16x16x32_bf16(a[mi], bfr[ni], acc[mi][ni], 0, 0, 0);
    }
    __syncthreads();
  }

  float bov[4];
#pragma unroll
  for (int ni = 0; ni < 4; ++ni) bov[ni] = bo[nloc0 + wn + ni * 16 + l15];
#pragma unroll
  for (int mi = 0; mi < 4; ++mi)
#pragma unroll
    for (int ni = 0; ni < 4; ++ni)
#pragma unroll
      for (int r = 0; r < 4; ++r) {
        const int grow = m0 + wm + mi * 16 + l16 * 4 + r;
        const int gcol = nloc0 + wn + ni * 16 + l15;
        const size_t o = (size_t)grow * 256 + gcol;
        out[o] = (acc[mi][ni][r] + bov[ni]) * (float)gateb[o];
      }
}

extern "C" void kernel_launch(void* const* d_in, const int* in_sizes, int n_in,
                              void* d_out, int out_size, void* d_ws, size_t ws_size,
                              hipStream_t stream)
{
  const float* msa  = (const float*)d_in[0];
  const float* pair = (const float*)d_in[1];
  const int*   mask = (const int*)d_in[2];
  const float* ln_g = (const float*)d_in[3];
  const float* ln_b = (const float*)d_in[4];
  const float* Wq = (const float*)d_in[5];  const float* bq = (const float*)d_in[6];
  const float* Wk = (const float*)d_in[7];  const float* bk = (const float*)d_in[8];
  const float* Wv = (const float*)d_in[9];  const float* bv = (const float*)d_in[10];
  const float* Wb = (const float*)d_in[11]; const float* bb = (const float*)d_in[12];
  const float* Wo = (const float*)d_in[13]; const float* bo = (const float*)d_in[14];
  const float* Wg = (const float*)d_in[15]; const float* bg = (const float*)d_in[16];
  float* out = (float*)d_out;

  char* ws = (char*)d_ws;
  __bf16* xn    = (__bf16*)(ws);
  __bf16* qb    = (__bf16*)(ws + 16777216);
  __bf16* kb    = (__bf16*)(ws + 2 * 16777216);
  __bf16* vb    = (__bf16*)(ws + 3 * 16777216);
  __bf16* opre  = (__bf16*)(ws + 4 * 16777216);
  __bf16* Wt    = (__bf16*)(ws + 5 * 16777216);                      // 640KB
  __bf16* gateb = (__bf16*)(ws + 5 * 16777216 + 655360);             // 16.8MB
  float*  biasP = (float*)(ws + 5 * 16777216 + 655360 + 16777216);   // 2MB packed

  hipLaunchKernelGGL(setup_kernel, dim3(11520), dim3(256), 0, stream,
                     msa, ln_g, ln_b, xn, pair, Wb, bb, biasP, Wq, Wk, Wv, Wg, Wo, Wt);
  hipLaunchKernelGGL(qkvg_gemm,   dim3(1024), dim3(512), 0, stream, xn, Wt, bq, bk, bv, bg, qb, kb, vb, gateb);
  hipLaunchKernelGGL(attn_kernel, dim3(1024), dim3(512), 0, stream, qb, kb, vb, biasP, mask, opre);
  hipLaunchKernelGGL(wo_gemm,     dim3(512),  dim3(256), 0, stream, opre, Wt + 4 * 65536, bo, gateb, out);
}